// Round 1
// baseline (417.669 us; speedup 1.0000x reference)
//
#include <hip/hip_runtime.h>
#include <hip/hip_bf16.h>

typedef __attribute__((ext_vector_type(8))) short bf16x8;
typedef __attribute__((ext_vector_type(4))) short shortx4;
typedef __attribute__((ext_vector_type(4))) float floatx4;

// ---------- helpers ----------

__device__ __forceinline__ unsigned short f2b(float f) {
    union { float f; unsigned int u; } v; v.f = f;
    unsigned int r = (v.u + 0x7FFFu + ((v.u >> 16) & 1u)) >> 16;
    return (unsigned short)r;
}

__device__ __forceinline__ void gload_lds16(const void* g, void* l) {
    __builtin_amdgcn_global_load_lds(
        (const __attribute__((address_space(1))) void*)g,
        (__attribute__((address_space(3))) void*)l, 16, 0, 0);
}

// ---------- fp32 -> bf16 convert ----------

__global__ __launch_bounds__(256) void f2b_kernel(const float* __restrict__ in,
                                                  unsigned short* __restrict__ out,
                                                  int n) {
    int i = (blockIdx.x * 256 + threadIdx.x) * 4;
    if (i >= n) return;
    floatx4 v = *(const floatx4*)&in[i];
    shortx4 o;
    o[0] = (short)f2b(v[0]); o[1] = (short)f2b(v[1]);
    o[2] = (short)f2b(v[2]); o[3] = (short)f2b(v[3]);
    *(shortx4*)&out[i] = o;
}

// ---------- GEMM: C[M,N] = A[M,K] @ B[N,K]^T  (m97 structure) ----------
// MODE 0: epilogue routes cols into Q [h][n][64], K [h][n][64], Vt [h][64][n] (bf16)
// MODE 1: epilogue writes fp32 C + bias

template <int MODE>
__global__ __launch_bounds__(256) void gemm_bt(
    const unsigned short* __restrict__ A, const unsigned short* __restrict__ B,
    int M, int N, int K,
    unsigned short* __restrict__ Qo, unsigned short* __restrict__ Ko,
    unsigned short* __restrict__ Vt,
    float* __restrict__ Cout, const float* __restrict__ bias)
{
    __shared__ unsigned short As[128 * 64];
    __shared__ unsigned short Bs[128 * 64];

    const int t = threadIdx.x;
    const int lane = t & 63, wid = t >> 6;
    const int wr = wid >> 1, wc = wid & 1;
    const int nbn = N >> 7;

    // XCD-aware swizzle (nwg % 8 == 0 for both our launches)
    const int nwg = gridDim.x;
    const int cpx = nwg >> 3;
    const int gid = blockIdx.x;
    const int swz = (gid & 7) * cpx + (gid >> 3);
    const int m0 = (swz / nbn) << 7;
    const int n0 = (swz % nbn) << 7;

    floatx4 acc[4][4];
#pragma unroll
    for (int i = 0; i < 4; i++)
#pragma unroll
        for (int j = 0; j < 4; j++) acc[i][j] = (floatx4)0.0f;

    const int row_s = t >> 3;   // 0..31
    const int ch = t & 7;       // 16B chunk within a 64-elem row

    const int nkt = K >> 6;
    for (int kt = 0; kt < nkt; ++kt) {
        const int k0 = kt << 6;
#pragma unroll
        for (int it = 0; it < 4; ++it) {
            const int row = row_s + it * 32;
            gload_lds16(A + (size_t)(m0 + row) * K + k0 + ch * 8, &As[row * 64 + ch * 8]);
            gload_lds16(B + (size_t)(n0 + row) * K + k0 + ch * 8, &Bs[row * 64 + ch * 8]);
        }
        __syncthreads();
#pragma unroll
        for (int ks = 0; ks < 2; ++ks) {
            bf16x8 a[4], b[4];
#pragma unroll
            for (int i = 0; i < 4; i++)
                a[i] = *(const bf16x8*)&As[(64 * wr + 16 * i + (lane & 15)) * 64 + ks * 32 + (lane >> 4) * 8];
#pragma unroll
            for (int j = 0; j < 4; j++)
                b[j] = *(const bf16x8*)&Bs[(64 * wc + 16 * j + (lane & 15)) * 64 + ks * 32 + (lane >> 4) * 8];
#pragma unroll
            for (int i = 0; i < 4; i++)
#pragma unroll
                for (int j = 0; j < 4; j++)
                    acc[i][j] = __builtin_amdgcn_mfma_f32_16x16x32_bf16(a[i], b[j], acc[i][j], 0, 0, 0);
        }
        __syncthreads();
    }

    // epilogue: D row = (lane>>4)*4 + r, col = lane&15 within each 16x16 frag
#pragma unroll
    for (int i = 0; i < 4; i++) {
        const int mrow = m0 + 64 * wr + 16 * i + ((lane >> 4) << 2);
#pragma unroll
        for (int j = 0; j < 4; j++) {
            const int col = n0 + 64 * wc + 16 * j + (lane & 15);
            if (MODE == 0) {
                const int sel = col >> 10;        // 0=q 1=k 2=v (uniform per frag)
                const int h = (col >> 6) & 15;    // uniform per frag
                const int d = col & 63;
                const int bb = mrow >> 11;        // batch (tile never crosses)
                const int n = mrow & 2047;
                const int bh = bb * 16 + h;
                if (sel == 2) {
                    shortx4 v;
#pragma unroll
                    for (int r = 0; r < 4; r++) v[r] = (short)f2b(acc[i][j][r]);
                    *(shortx4*)&Vt[(size_t)(bh * 64 + d) * 2048 + n] = v;
                } else {
                    unsigned short* dst = (sel == 0 ? Qo : Ko) + (size_t)(bh * 2048 + n) * 64 + d;
#pragma unroll
                    for (int r = 0; r < 4; r++) dst[(size_t)r * 64] = f2b(acc[i][j][r]);
                }
            } else {
                const float bi = bias[col];
#pragma unroll
                for (int r = 0; r < 4; r++)
                    Cout[(size_t)(mrow + r) * N + col] = acc[i][j][r] + bi;
            }
        }
    }
}

// ---------- flash attention ----------
// Q,K: [64 heads][2048][64] bf16 ; Vt: [64 heads][64][2048] bf16
// O: [b=4][n=2048][h*64=1024] bf16
// grid = 1024 blocks (head x 16 q-tiles), 256 threads (4 waves x 32 q-rows)

__global__ __launch_bounds__(256) void attn_kernel(
    const unsigned short* __restrict__ Q, const unsigned short* __restrict__ Kp,
    const unsigned short* __restrict__ Vt, unsigned short* __restrict__ O)
{
    __shared__ unsigned short Ks[64 * 64];
    __shared__ unsigned short Vs[64 * 64];
    __shared__ unsigned short Ps[4 * 32 * 64];

    const int t = threadIdx.x, lane = t & 63, w = t >> 6;
    const int bid = blockIdx.x;
    // XCD-locality mapping: head % 8 pinned per XCD slot
    const int x = bid & 7, seq = bid >> 3;
    const int head = x + 8 * (seq & 7);   // 0..63
    const int qb = seq >> 3;              // 0..15
    const size_t base_nd = (size_t)head * 2048 * 64;
    const int q0 = qb * 128 + w * 32;

    // Q fragments in registers (A operand)
    bf16x8 aq[2][2];
#pragma unroll
    for (int rb = 0; rb < 2; rb++)
#pragma unroll
        for (int ks = 0; ks < 2; ks++)
            aq[rb][ks] = *(const bf16x8*)&Q[base_nd + (size_t)(q0 + 16 * rb + (lane & 15)) * 64 + ks * 32 + (lane >> 4) * 8];

    floatx4 o[2][4];
    float m_st[2][4], l_st[2][4];
#pragma unroll
    for (int rb = 0; rb < 2; rb++) {
#pragma unroll
        for (int db = 0; db < 4; db++) o[rb][db] = (floatx4)0.0f;
#pragma unroll
        for (int r = 0; r < 4; r++) { m_st[rb][r] = -INFINITY; l_st[rb][r] = 0.0f; }
    }

    const float sc = 0.18033688011112042f;  // (1/8) * log2(e)

    char* KsB = (char*)Ks;
    char* VsB = (char*)Vs;
    char* PsB = (char*)&Ps[w * 32 * 64];

    for (int nt = 0; nt < 32; ++nt) {
        const int n0 = nt * 64;
        // stage K tile [64 n][64 d] and Vt tile [64 d][64 n], XOR-swizzled
        {
            bf16x8 kreg[2], vreg[2];
            int dsts[2];
#pragma unroll
            for (int it = 0; it < 2; ++it) {
                const int idx = it * 256 + t;           // 0..511
                const int row = idx >> 3, c = idx & 7;
                kreg[it] = *(const bf16x8*)&Kp[base_nd + (size_t)(n0 + row) * 64 + c * 8];
                vreg[it] = *(const bf16x8*)&Vt[base_nd + (size_t)row * 2048 + n0 + c * 8];
                dsts[it] = (row * 128 + c * 16) ^ ((row & 7) << 4);
            }
#pragma unroll
            for (int it = 0; it < 2; ++it) {
                *(bf16x8*)(KsB + dsts[it]) = kreg[it];
                *(bf16x8*)(VsB + dsts[it]) = vreg[it];
            }
        }
        __syncthreads();

        // S = Q @ K^T
        floatx4 s[2][4];
#pragma unroll
        for (int rb = 0; rb < 2; rb++)
#pragma unroll
            for (int j = 0; j < 4; j++) s[rb][j] = (floatx4)0.0f;
#pragma unroll
        for (int ks = 0; ks < 2; ++ks) {
            bf16x8 bk[4];
#pragma unroll
            for (int j = 0; j < 4; j++) {
                const int row = 16 * j + (lane & 15);
                const int off = (row * 128 + ks * 64 + (lane >> 4) * 16) ^ ((row & 7) << 4);
                bk[j] = *(const bf16x8*)(KsB + off);
            }
#pragma unroll
            for (int rb = 0; rb < 2; rb++)
#pragma unroll
                for (int j = 0; j < 4; j++)
                    s[rb][j] = __builtin_amdgcn_mfma_f32_16x16x32_bf16(aq[rb][ks], bk[j], s[rb][j], 0, 0, 0);
        }

        // online softmax (exp2 form; scale folded into one FMA per element)
#pragma unroll
        for (int rb = 0; rb < 2; rb++) {
            float corr[4], mb[4], rs[4];
#pragma unroll
            for (int r = 0; r < 4; r++) {
                float v = fmaxf(fmaxf(s[rb][0][r], s[rb][1][r]), fmaxf(s[rb][2][r], s[rb][3][r]));
                v = fmaxf(v, __shfl_xor(v, 1));
                v = fmaxf(v, __shfl_xor(v, 2));
                v = fmaxf(v, __shfl_xor(v, 4));
                v = fmaxf(v, __shfl_xor(v, 8));
                const float mnew = fmaxf(m_st[rb][r], v);
                corr[r] = __builtin_amdgcn_exp2f((m_st[rb][r] - mnew) * sc);
                mb[r] = mnew * sc;
                m_st[rb][r] = mnew;
                rs[r] = 0.0f;
            }
            const int prow_base = 16 * rb + ((lane >> 4) << 2);
#pragma unroll
            for (int j = 0; j < 4; j++) {
                const int col = 16 * j + (lane & 15);
#pragma unroll
                for (int r = 0; r < 4; r++) {
                    const float p = __builtin_amdgcn_exp2f(fmaf(s[rb][j][r], sc, -mb[r]));
                    rs[r] += p;
                    const int row = prow_base + r;
                    const int off = (row * 128 + col * 2) ^ ((row & 7) << 4);
                    *(unsigned short*)(PsB + off) = f2b(p);
                }
            }
#pragma unroll
            for (int r = 0; r < 4; r++) {
                float v = rs[r];
                v += __shfl_xor(v, 1);
                v += __shfl_xor(v, 2);
                v += __shfl_xor(v, 4);
                v += __shfl_xor(v, 8);
                l_st[rb][r] = l_st[rb][r] * corr[r] + v;
            }
#pragma unroll
            for (int db = 0; db < 4; db++)
#pragma unroll
                for (int r = 0; r < 4; r++) o[rb][db][r] *= corr[r];
        }

        // O += P @ V   (B operand from Vt tile, contiguous reads)
#pragma unroll
        for (int ks = 0; ks < 2; ++ks) {
            bf16x8 ap[2], bv[4];
#pragma unroll
            for (int rb = 0; rb < 2; rb++) {
                const int row = 16 * rb + (lane & 15);
                const int off = (row * 128 + ks * 64 + (lane >> 4) * 16) ^ ((row & 7) << 4);
                ap[rb] = *(const bf16x8*)(PsB + off);
            }
#pragma unroll
            for (int db = 0; db < 4; db++) {
                const int row = 16 * db + (lane & 15);
                const int off = (row * 128 + ks * 64 + (lane >> 4) * 16) ^ ((row & 7) << 4);
                bv[db] = *(const bf16x8*)(VsB + off);
            }
#pragma unroll
            for (int rb = 0; rb < 2; rb++)
#pragma unroll
                for (int db = 0; db < 4; db++)
                    o[rb][db] = __builtin_amdgcn_mfma_f32_16x16x32_bf16(ap[rb], bv[db], o[rb][db], 0, 0, 0);
        }
        __syncthreads();
    }

    // write O (bf16, [b][n][h*64+d])
    const int bb = head >> 4, h = head & 15;
#pragma unroll
    for (int rb = 0; rb < 2; rb++)
#pragma unroll
        for (int db = 0; db < 4; db++)
#pragma unroll
            for (int r = 0; r < 4; r++) {
                const int row = q0 + 16 * rb + ((lane >> 4) << 2) + r;
                const int col = h * 64 + 16 * db + (lane & 15);
                const float v = o[rb][db][r] / l_st[rb][r];
                O[((size_t)(bb * 2048 + row)) * 1024 + col] = f2b(v);
            }
}

// ---------- launch ----------

extern "C" void kernel_launch(void* const* d_in, const int* in_sizes, int n_in,
                              void* d_out, int out_size, void* d_ws, size_t ws_size,
                              hipStream_t stream) {
    const float* x     = (const float*)d_in[0];
    const float* w_qkv = (const float*)d_in[1];
    const float* w_out = (const float*)d_in[2];
    const float* b_out = (const float*)d_in[3];
    float* out = (float*)d_out;

    unsigned short* xb  = (unsigned short*)d_ws;
    unsigned short* wqb = xb  + (size_t)8192 * 1024;
    unsigned short* wob = wqb + (size_t)3072 * 1024;
    unsigned short* q   = wob + (size_t)1024 * 1024;
    unsigned short* k   = q   + (size_t)64 * 2048 * 64;
    unsigned short* vt  = k   + (size_t)64 * 2048 * 64;
    unsigned short* ob  = vt  + (size_t)64 * 2048 * 64;

    f2b_kernel<<<8192, 256, 0, stream>>>(x, xb, 8192 * 1024);
    f2b_kernel<<<3072, 256, 0, stream>>>(w_qkv, wqb, 3072 * 1024);
    f2b_kernel<<<1024, 256, 0, stream>>>(w_out, wob, 1024 * 1024);

    gemm_bt<0><<<1536, 256, 0, stream>>>(xb, wqb, 8192, 3072, 1024,
                                         q, k, vt, nullptr, nullptr);
    attn_kernel<<<1024, 256, 0, stream>>>(q, k, vt, ob);
    gemm_bt<1><<<512, 256, 0, stream>>>(ob, wob, 8192, 1024, 1024,
                                        nullptr, nullptr, nullptr, out, b_out);
}